// Round 1
// baseline (203.551 us; speedup 1.0000x reference)
//
#include <hip/hip_runtime.h>
#include <hip/hip_bf16.h>
#include <math.h>

#define NN    8192
#define FDIM  64
#define EDGES 262144
#define BATCH 2
#define ALPHA 0.2f
#define MAXDEG 1024

// ---- workspace layout (byte offsets, all 256-aligned) ----
#define OFF_WH      0u          // float[B*N*64]   4 MB
#define OFF_S1      4194304u    // float[B*N]      64 KB
#define OFF_S2      4259840u    // float[B*N]      64 KB
#define OFF_VALS    4325376u    // float[B*E]      2 MB
#define OFF_COUNTS  6422528u    // int[N]          32 KB
#define OFF_CURSOR  6455296u    // int[N]          32 KB
#define OFF_ROWPTR  6488064u    // int[N+1]        (padded)
#define OFF_CSR     6521088u    // int[E]          1 MB

// Wh = h @ W^T, s1 = Wh . a[:64], s2 = Wh . a[64:]
__global__ __launch_bounds__(256) void prep_kernel(
    const float* __restrict__ h, const float* __restrict__ W,
    const float* __restrict__ a,
    float* __restrict__ Wh, float* __restrict__ s1, float* __restrict__ s2) {
  __shared__ float sW[64][65];   // +1 pad: lane-major read stays conflict-free
  __shared__ float sA[128];
  __shared__ float sH[4][64];
  int tid = threadIdx.x;
  for (int i = tid; i < 4096; i += 256) sW[i >> 6][i & 63] = W[i];
  if (tid < 128) sA[tid] = a[tid];
  int grp = tid >> 6, lane = tid & 63;
  int nn = blockIdx.x * 4 + grp;            // [0, B*N)
  sH[grp][lane] = h[(size_t)nn * 64 + lane];
  __syncthreads();
  float acc = 0.f;
#pragma unroll
  for (int k = 0; k < 64; ++k) acc += sH[grp][k] * sW[lane][k];
  Wh[(size_t)nn * 64 + lane] = acc;
  float p1 = acc * sA[lane];
  float p2 = acc * sA[64 + lane];
#pragma unroll
  for (int off = 32; off; off >>= 1) {
    p1 += __shfl_xor(p1, off, 64);
    p2 += __shfl_xor(p2, off, 64);
  }
  if (lane == 0) { s1[nn] = p1; s2[nn] = p2; }
}

__global__ void hist_kernel(const int* __restrict__ ei, int* __restrict__ counts) {
  int e = blockIdx.x * blockDim.x + threadIdx.x;
  if (e < EDGES) atomicAdd(&counts[ei[e]], 1);
}

// exclusive prefix sum of counts[0..N-1] -> row_ptr[0..N]
__global__ __launch_bounds__(1024) void scan_kernel(
    const int* __restrict__ counts, int* __restrict__ row_ptr) {
  __shared__ int part[1024];
  int tid = threadIdx.x;
  int local[8];
  int sum = 0;
#pragma unroll
  for (int i = 0; i < 8; ++i) { local[i] = counts[tid * 8 + i]; sum += local[i]; }
  part[tid] = sum;
  __syncthreads();
  for (int off = 1; off < 1024; off <<= 1) {
    int v = (tid >= off) ? part[tid - off] : 0;
    __syncthreads();
    part[tid] += v;
    __syncthreads();
  }
  int run = (tid == 0) ? 0 : part[tid - 1];
#pragma unroll
  for (int i = 0; i < 8; ++i) { row_ptr[tid * 8 + i] = run; run += local[i]; }
  if (tid == 1023) row_ptr[NN] = run;
}

__global__ void bucket_kernel(const int* __restrict__ ei,
                              const int* __restrict__ row_ptr,
                              int* __restrict__ cursor, int* __restrict__ csr) {
  int e = blockIdx.x * blockDim.x + threadIdx.x;
  if (e >= EDGES) return;
  int s = ei[e];
  int pos = row_ptr[s] + atomicAdd(&cursor[s], 1);
  csr[pos] = e;
}

__global__ void vals_kernel(const int* __restrict__ ei,
                            const float* __restrict__ ew,
                            const float* __restrict__ s1,
                            const float* __restrict__ s2,
                            float* __restrict__ vals) {
  int idx = blockIdx.x * blockDim.x + threadIdx.x;   // [0, B*E)
  int b = idx >> 18;                                 // E = 2^18
  int e = idx & (EDGES - 1);
  int s = ei[e], d = ei[EDGES + e];
  float x = s1[b * NN + s] + s2[b * NN + d];
  float lr = x > 0.f ? x : ALPHA * x;
  vals[idx] = lr * ew[e];
}

// one wave per (batch, src-row): dedupe (set semantics, last idx wins),
// masked softmax over winners, gather-accumulate Wh[dst], ELU, store.
__global__ __launch_bounds__(64) void row_kernel(
    const int* __restrict__ ei, const float* __restrict__ vals,
    const int* __restrict__ row_ptr, const int* __restrict__ csr,
    const float* __restrict__ Wh, float* __restrict__ out) {
  __shared__ int   s_eid[MAXDEG];
  __shared__ int   s_dst[MAXDEG];
  __shared__ float s_p[MAXDEG];
  int bn = blockIdx.x;
  int b = bn >> 13, n = bn & (NN - 1);
  int beg = row_ptr[n];
  int deg = row_ptr[n + 1] - beg;
  if (deg > MAXDEG) deg = MAXDEG;  // statistically unreachable guard
  int lane = threadIdx.x;

  for (int k = lane; k < deg; k += 64) {
    int e = csr[beg + k];
    s_eid[k] = e;
    s_dst[k] = ei[EDGES + e];
    s_p[k]   = vals[b * EDGES + e];
  }
  __syncthreads();

  // winner selection (largest edge idx per (src,dst)) + local max
  float m = -INFINITY;
  for (int k = lane; k < deg; k += 64) {
    int d = s_dst[k], id = s_eid[k];
    bool win = true;
    for (int j = 0; j < deg; ++j)
      if (s_dst[j] == d && s_eid[j] > id) { win = false; break; }
    float v = s_p[k];
    if (win && v != 0.f) m = fmaxf(m, v);
    else s_p[k] = 0.f;     // masked / loser sentinel (only owner lane touches k)
  }
#pragma unroll
  for (int off = 32; off; off >>= 1) m = fmaxf(m, __shfl_xor(m, off, 64));
  __syncthreads();

  float lsum = 0.f;
  for (int k = lane; k < deg; k += 64) {
    float v = s_p[k];
    float p = (v != 0.f) ? expf(v - m) : 0.f;
    s_p[k] = p;
    lsum += p;
  }
#pragma unroll
  for (int off = 32; off; off >>= 1) lsum += __shfl_xor(lsum, off, 64);
  __syncthreads();

  float inv = lsum > 0.f ? 1.f / lsum : 0.f;
  float acc = 0.f;
  for (int k = 0; k < deg; ++k) {
    float p = s_p[k];                 // wave-uniform
    if (p != 0.f)
      acc += (p * inv) * Wh[((size_t)b * NN + s_dst[k]) * 64 + lane];
  }
  float o = acc > 0.f ? acc : expm1f(acc);
  out[(size_t)bn * 64 + lane] = o;
}

extern "C" void kernel_launch(void* const* d_in, const int* in_sizes, int n_in,
                              void* d_out, int out_size, void* d_ws, size_t ws_size,
                              hipStream_t stream) {
  const float* h  = (const float*)d_in[0];
  const float* W  = (const float*)d_in[1];
  const float* a  = (const float*)d_in[2];
  const int*   ei = (const int*)d_in[3];
  const float* ew = (const float*)d_in[4];
  float* out = (float*)d_out;

  char* ws = (char*)d_ws;
  float* Wh      = (float*)(ws + OFF_WH);
  float* s1      = (float*)(ws + OFF_S1);
  float* s2      = (float*)(ws + OFF_S2);
  float* vals    = (float*)(ws + OFF_VALS);
  int*   counts  = (int*)(ws + OFF_COUNTS);
  int*   cursor  = (int*)(ws + OFF_CURSOR);
  int*   row_ptr = (int*)(ws + OFF_ROWPTR);
  int*   csr     = (int*)(ws + OFF_CSR);

  // zero counts + cursor (contiguous 64 KB)
  hipMemsetAsync(ws + OFF_COUNTS, 0, 65536, stream);

  prep_kernel<<<BATCH * NN / 4, 256, 0, stream>>>(h, W, a, Wh, s1, s2);
  hist_kernel<<<EDGES / 256, 256, 0, stream>>>(ei, counts);
  scan_kernel<<<1, 1024, 0, stream>>>(counts, row_ptr);
  bucket_kernel<<<EDGES / 256, 256, 0, stream>>>(ei, row_ptr, cursor, csr);
  vals_kernel<<<BATCH * EDGES / 256, 256, 0, stream>>>(ei, ew, s1, s2, vals);
  row_kernel<<<BATCH * NN, 64, 0, stream>>>(ei, vals, row_ptr, csr, Wh, out);
}

// Round 2
// 123.886 us; speedup vs baseline: 1.6430x; 1.6430x over previous
//
#include <hip/hip_runtime.h>
#include <hip/hip_bf16.h>
#include <math.h>

#define NN    8192
#define FDIM  64
#define EDGES 262144
#define BATCH 2
#define ALPHA 0.2f
#define CAP   96          // bucket capacity; P(deg>96) ~ 1e-18 per row (Poisson mean 32)

// ---- workspace layout (byte offsets) ----
#define OFF_WH   0u           // float[B*N*64]   4 MB
#define OFF_S1   4194304u     // float[B*N]      64 KB
#define OFF_S2   4259840u     // float[B*N]      64 KB
#define OFF_CNT  4325376u     // int[N]          32 KB
#define OFF_CSR  4358144u     // uint[N*96]      3 MB   (total 7.50 MB, <= proven ws)

#define PREP_BLOCKS   256
#define BUCKET_BLOCKS 1024    // 1024*256 = EDGES

// Fused: [0,256) blocks do Wh = h@W^T + s1/s2; [256,1280) bucket edges by src.
// Bucket entries pack (e<<14)|dst: same dst => dedupe winner == max packed.
__global__ __launch_bounds__(256) void stage1_kernel(
    const float* __restrict__ h, const float* __restrict__ W,
    const float* __restrict__ a, const int* __restrict__ ei,
    float* __restrict__ Wh, float* __restrict__ s1, float* __restrict__ s2,
    int* __restrict__ cnt, unsigned int* __restrict__ csr) {
  int tid = threadIdx.x;
  if (blockIdx.x >= PREP_BLOCKS) {
    int e = (blockIdx.x - PREP_BLOCKS) * 256 + tid;
    int s = ei[e], d = ei[EDGES + e];
    int pos = atomicAdd(&cnt[s], 1);
    if (pos < CAP) csr[s * CAP + pos] = ((unsigned int)e << 14) | (unsigned int)d;
    return;
  }
  int lane = tid & 63;
  int w = __builtin_amdgcn_readfirstlane(blockIdx.x * 4 + (tid >> 6)); // [0,1024)
  // lane-private W row: W[lane][0..63]
  float wreg[64];
  {
    const float4* W4 = (const float4*)(W + lane * 64);
#pragma unroll
    for (int i = 0; i < 16; ++i) {
      float4 v = W4[i];
      wreg[4 * i] = v.x; wreg[4 * i + 1] = v.y; wreg[4 * i + 2] = v.z; wreg[4 * i + 3] = v.w;
    }
  }
  float a1 = a[lane], a2 = a[64 + lane];
  for (int r = 0; r < 16; ++r) {
    int nn = w * 16 + r;                       // [0, B*N)
    const float4* h4 = (const float4*)(h + (size_t)nn * 64);  // wave-uniform addr
    float acc = 0.f;
#pragma unroll
    for (int k4 = 0; k4 < 16; ++k4) {
      float4 hv = h4[k4];
      acc += hv.x * wreg[4 * k4] + hv.y * wreg[4 * k4 + 1] +
             hv.z * wreg[4 * k4 + 2] + hv.w * wreg[4 * k4 + 3];
    }
    Wh[(size_t)nn * 64 + lane] = acc;
    float p1 = acc * a1, p2 = acc * a2;
#pragma unroll
    for (int off = 32; off; off >>= 1) {
      p1 += __shfl_xor(p1, off, 64);
      p2 += __shfl_xor(p2, off, 64);
    }
    if (lane == 0) { s1[nn] = p1; s2[nn] = p2; }
  }
}

// One wave per (batch,row). Everything in registers; no LDS, no __syncthreads.
__global__ __launch_bounds__(256) void row_kernel(
    const float* __restrict__ ew, const float* __restrict__ s1,
    const float* __restrict__ s2, const int* __restrict__ cnt,
    const unsigned int* __restrict__ csr, const float* __restrict__ Wh,
    float* __restrict__ out) {
  int lane = threadIdx.x & 63;
  int idx = blockIdx.x * 4 + (threadIdx.x >> 6);   // [0, B*N)
  int b = idx >> 13, n = idx & (NN - 1);
  int deg = cnt[n]; if (deg > CAP) deg = CAP;

  const float* s2b = s2 + b * NN;
  float s1n = s1[b * NN + n];

  unsigned int pk0 = 0xFFFFFFFFu, pk1 = 0xFFFFFFFFu;
  if (lane < deg)      pk0 = csr[n * CAP + lane];
  if (lane + 64 < deg) pk1 = csr[n * CAP + lane + 64];

  // per-edge value: leaky_relu(s1[src]+s2[dst]) * ew[e]; 0 => masked
  float v0 = 0.f, v1 = 0.f;
  if (lane < deg) {
    int d0 = pk0 & 0x3FFFu, e0 = pk0 >> 14;
    float x = s1n + s2b[d0];
    v0 = (x > 0.f ? x : ALPHA * x) * ew[e0];
  }
  if (lane + 64 < deg) {
    int d1 = pk1 & 0x3FFFu, e1 = pk1 >> 14;
    float x = s1n + s2b[d1];
    v1 = (x > 0.f ? x : ALPHA * x) * ew[e1];
  }

  // dedupe: loser iff another entry has same dst (low 14 bits) and larger packed
  if (deg <= 64) {
    for (int j = 0; j < deg; ++j) {
      unsigned int q = __shfl(pk0, j, 64);
      if ((((q ^ pk0) & 0x3FFFu) == 0u) & (q > pk0)) v0 = 0.f;
    }
  } else {
    for (int j = 0; j < 64; ++j) {
      unsigned int q = __shfl(pk0, j, 64);
      if ((((q ^ pk0) & 0x3FFFu) == 0u) & (q > pk0)) v0 = 0.f;
      if ((((q ^ pk1) & 0x3FFFu) == 0u) & (q > pk1)) v1 = 0.f;
    }
    for (int j = 0; j < deg - 64; ++j) {
      unsigned int q = __shfl(pk1, j, 64);
      if ((((q ^ pk0) & 0x3FFFu) == 0u) & (q > pk0)) v0 = 0.f;
      if ((((q ^ pk1) & 0x3FFFu) == 0u) & (q > pk1)) v1 = 0.f;
    }
  }

  // masked softmax over {v != 0}
  float m = (v0 != 0.f) ? v0 : -INFINITY;
  if (deg > 64) { float t = (v1 != 0.f) ? v1 : -INFINITY; m = fmaxf(m, t); }
#pragma unroll
  for (int off = 32; off; off >>= 1) m = fmaxf(m, __shfl_xor(m, off, 64));

  float p0 = (v0 != 0.f) ? expf(v0 - m) : 0.f;
  float p1 = (deg > 64 && v1 != 0.f) ? expf(v1 - m) : 0.f;
  float sum = p0 + p1;
#pragma unroll
  for (int off = 32; off; off >>= 1) sum += __shfl_xor(sum, off, 64);
  float inv = (sum > 0.f) ? 1.f / sum : 0.f;

  // gather-accumulate: unconditional FMA (p==0 entries contribute nothing)
  const float* Whb = Wh + (size_t)b * NN * FDIM;
  int dst0 = (int)(pk0 & 0x3FFFu);
  float acc = 0.f;
  int d64 = deg < 64 ? deg : 64;
  int k = 0;
  for (; k + 8 <= d64; k += 8) {
#pragma unroll
    for (int i = 0; i < 8; ++i) {
      float pw = __shfl(p0, k + i, 64);
      int   dd = __shfl(dst0, k + i, 64);
      acc += pw * Whb[dd * 64 + lane];
    }
  }
  for (; k < d64; ++k) {
    float pw = __shfl(p0, k, 64);
    int   dd = __shfl(dst0, k, 64);
    acc += pw * Whb[dd * 64 + lane];
  }
  if (deg > 64) {
    int dst1 = (int)(pk1 & 0x3FFFu);
    for (int k2 = 0; k2 < deg - 64; ++k2) {
      float pw = __shfl(p1, k2, 64);
      int   dd = __shfl(dst1, k2, 64);
      acc += pw * Whb[dd * 64 + lane];
    }
  }
  acc *= inv;
  out[(size_t)idx * 64 + lane] = acc > 0.f ? acc : expm1f(acc);
}

extern "C" void kernel_launch(void* const* d_in, const int* in_sizes, int n_in,
                              void* d_out, int out_size, void* d_ws, size_t ws_size,
                              hipStream_t stream) {
  const float* h  = (const float*)d_in[0];
  const float* W  = (const float*)d_in[1];
  const float* a  = (const float*)d_in[2];
  const int*   ei = (const int*)d_in[3];
  const float* ew = (const float*)d_in[4];
  float* out = (float*)d_out;

  char* ws = (char*)d_ws;
  float*        Wh  = (float*)(ws + OFF_WH);
  float*        s1  = (float*)(ws + OFF_S1);
  float*        s2  = (float*)(ws + OFF_S2);
  int*          cnt = (int*)(ws + OFF_CNT);
  unsigned int* csr = (unsigned int*)(ws + OFF_CSR);

  hipMemsetAsync(cnt, 0, NN * sizeof(int), stream);
  stage1_kernel<<<PREP_BLOCKS + BUCKET_BLOCKS, 256, 0, stream>>>(
      h, W, a, ei, Wh, s1, s2, cnt, csr);
  row_kernel<<<BATCH * NN / 4, 256, 0, stream>>>(ew, s1, s2, cnt, csr, Wh, out);
}